// Round 2
// baseline (246.540 us; speedup 1.0000x reference)
//
#include <hip/hip_runtime.h>
#include <hip/hip_bf16.h>
#include <stdint.h>

typedef unsigned short ushort_t;

// ---------------------------------------------------------------------------
// Pre-kernel: convert W1d (1024x64 fp32) into bf16, transposed to
// Wt[g][k][o][j]  (g=group 0..7, k=c-block 0..7, o=0..127, j=c within block)
// so the fused kernel's conv1d loads are coalesced 16B per lane.
// ---------------------------------------------------------------------------
__global__ void __launch_bounds__(256) w1d_to_bf16(const float* __restrict__ W1d,
                                                   ushort_t* __restrict__ Wt) {
    int t = blockIdx.x * 256 + threadIdx.x;      // 0..8191
    int g = t >> 10, k = (t >> 7) & 7, o = t & 127;
    const float* src = W1d + (((g << 7) + o) << 6) + (k << 3);
    ushort_t* dst = Wt + ((((g << 3) + k) << 7) + o) * 8;
#pragma unroll
    for (int j = 0; j < 8; ++j) {
        uint32_t u = __float_as_uint(src[j]);
        uint32_t r = (u + 0x7FFFu + ((u >> 16) & 1u)) >> 16;   // RN to bf16
        dst[j] = (ushort_t)r;
    }
}

__device__ __forceinline__ float lo16f(uint32_t u) { return __uint_as_float(u << 16); }
__device__ __forceinline__ float hi16f(uint32_t u) { return __uint_as_float(u & 0xFFFF0000u); }
__device__ __forceinline__ uint32_t pk_bf16(float a, float b) {
    uint32_t r;
    asm("v_cvt_pk_bf16_f32 %0, %1, %2" : "=v"(r) : "v"(a), "v"(b));
    return r;   // lo16 = bf16(a), hi16 = bf16(b)
}

// ---------------------------------------------------------------------------
// Fused kernel: one block per (b,h).  x tile read once from HBM, held in LDS
// as bf16 (rows padded to 49 uint4 = 784 B).
//   phase 1: stage x[b,h] (32x384) -> bf16 LDS
//   phase 2: y[e][w] = x[w,:].W2d[e,:] + b2d   (2 full-K outputs per thread)
//   phase 3: z[g][o] = Wg[g,o,:].y[g,:] + b1d ; softmax -> attn in LDS
//   phase 4: out[u,:] = sum_v attn[u][v] * x[v,:]
// LDS total = 25088 + 2048 + 4096 = 31232 B  ->  5 blocks/CU.
// ---------------------------------------------------------------------------
template <bool WBF>
__global__ void __launch_bounds__(256, 5) dynamixer_fused(
    const float* __restrict__ x,
    const float* __restrict__ W2d,
    const float* __restrict__ b2d,
    const float* __restrict__ W1d,
    const float* __restrict__ b1d,
    const ushort_t* __restrict__ Wt,
    float* __restrict__ out)
{
    __shared__ uint4 xs4[32 * 49];          // bf16 x tile, row stride 49 uint4
    __shared__ alignas(16) float ys[512];   // y, flat index e*32+w == g*64+c
    __shared__ float zs[32 * 32];           // attn[u][v]

    const int t = threadIdx.x;
    const int blk = blockIdx.x;                          // b*32 + h
    const float* __restrict__ xsrc = x + (size_t)blk * (32 * 384);
    ushort_t* const xs16 = (ushort_t*)xs4;

    // ---------------- phase 1: stage x as bf16 ----------------
    {
        const float4* __restrict__ s4 = (const float4*)xsrc;
#pragma unroll
        for (int k = 0; k < 6; ++k) {
            int p = t + (k << 8);                        // pair index 0..1535
            int row = p / 48, c = p - row * 48;          // 48 chunks of 8 bf16/row
            float4 A = s4[2 * p];
            float4 B = s4[2 * p + 1];
            uint4 pk;
            pk.x = pk_bf16(A.x, A.y);
            pk.y = pk_bf16(A.z, A.w);
            pk.z = pk_bf16(B.x, B.y);
            pk.w = pk_bf16(B.z, B.w);
            xs4[row * 49 + c] = pk;
        }
    }
    __syncthreads();

    // ---------------- phase 2: conv2d (y), 2 full-K outputs/thread ----------
    {
        const int ep = t >> 5, w = t & 31;               // e = 2ep, 2ep+1
        const uint4* __restrict__ xr = xs4 + w * 49;
        const float4* __restrict__ w2 = (const float4*)W2d;   // [16][96] f4
        const float4* __restrict__ wr0 = w2 + (2 * ep) * 96;
        const float4* __restrict__ wr1 = wr0 + 96;
        float acc0 = 0.f, acc1 = 0.f;
#pragma unroll 8
        for (int i = 0; i < 48; ++i) {
            uint4 xv = xr[i];
            float x0 = lo16f(xv.x), x1 = hi16f(xv.x);
            float x2 = lo16f(xv.y), x3 = hi16f(xv.y);
            float x4 = lo16f(xv.z), x5 = hi16f(xv.z);
            float x6 = lo16f(xv.w), x7 = hi16f(xv.w);
            float4 a0 = wr0[2 * i], a1 = wr0[2 * i + 1];
            float4 b0 = wr1[2 * i], b1 = wr1[2 * i + 1];
            acc0 += a0.x * x0; acc0 += a0.y * x1; acc0 += a0.z * x2; acc0 += a0.w * x3;
            acc0 += a1.x * x4; acc0 += a1.y * x5; acc0 += a1.z * x6; acc0 += a1.w * x7;
            acc1 += b0.x * x0; acc1 += b0.y * x1; acc1 += b0.z * x2; acc1 += b0.w * x3;
            acc1 += b1.x * x4; acc1 += b1.y * x5; acc1 += b1.z * x6; acc1 += b1.w * x7;
        }
        ys[(2 * ep) * 32 + w]     = acc0 + b2d[2 * ep];
        ys[(2 * ep + 1) * 32 + w] = acc1 + b2d[2 * ep + 1];
    }
    __syncthreads();

    // ---------------- phase 3: conv1d (z) + softmax -> attn ----------------
    {
        const int g = t >> 5, l = t & 31;
        float acc[4] = {0.f, 0.f, 0.f, 0.f};
        if (WBF) {
            const uint4* __restrict__ wp = (const uint4*)Wt + (g << 10);
#pragma unroll
            for (int k = 0; k < 8; ++k) {
                float4 ya = *(const float4*)&ys[(g << 6) + (k << 3)];
                float4 yb = *(const float4*)&ys[(g << 6) + (k << 3) + 4];
#pragma unroll
                for (int j = 0; j < 4; ++j) {
                    uint4 wv = wp[(k << 7) + l + (j << 5)];
                    acc[j] += lo16f(wv.x) * ya.x; acc[j] += hi16f(wv.x) * ya.y;
                    acc[j] += lo16f(wv.y) * ya.z; acc[j] += hi16f(wv.y) * ya.w;
                    acc[j] += lo16f(wv.z) * yb.x; acc[j] += hi16f(wv.z) * yb.y;
                    acc[j] += lo16f(wv.w) * yb.z; acc[j] += hi16f(wv.w) * yb.w;
                }
            }
        } else {
#pragma unroll
            for (int k = 0; k < 8; ++k) {
                float4 ya = *(const float4*)&ys[(g << 6) + (k << 3)];
                float4 yb = *(const float4*)&ys[(g << 6) + (k << 3) + 4];
#pragma unroll
                for (int j = 0; j < 4; ++j) {
                    const float* wr = W1d + (((g << 7) + l + (j << 5)) << 6) + (k << 3);
                    float4 wa = *(const float4*)wr;
                    float4 wb = *(const float4*)(wr + 4);
                    acc[j] += wa.x * ya.x; acc[j] += wa.y * ya.y;
                    acc[j] += wa.z * ya.z; acc[j] += wa.w * ya.w;
                    acc[j] += wb.x * yb.x; acc[j] += wb.y * yb.y;
                    acc[j] += wb.z * yb.z; acc[j] += wb.w * yb.w;
                }
            }
        }
#pragma unroll
        for (int j = 0; j < 4; ++j) acc[j] += b1d[(g << 7) + (j << 5) + l];

        // softmax over v (= lane within 32-lane group), one row per acc[j]
#pragma unroll
        for (int j = 0; j < 4; ++j) {
            float m = acc[j];
#pragma unroll
            for (int s = 16; s >= 1; s >>= 1) m = fmaxf(m, __shfl_xor(m, s, 32));
            float p = __expf(acc[j] - m);
            float ssum = p;
#pragma unroll
            for (int s = 16; s >= 1; s >>= 1) ssum += __shfl_xor(ssum, s, 32);
            zs[(((g << 2) + j) << 5) + l] = __fdividef(p, ssum);
        }
    }
    __syncthreads();

    // ---------------- phase 4: mixing out = attn . x ----------------
    {
        const int ug = t >> 5, l = t & 31;               // d-slice = 12 floats at l*12
        float acc[4][12];
#pragma unroll
        for (int j = 0; j < 4; ++j)
#pragma unroll
            for (int m = 0; m < 12; ++m) acc[j][m] = 0.f;

        for (int v = 0; v < 32; ++v) {
            const uint2* __restrict__ xp = (const uint2*)(xs16 + v * 392 + l * 12);
            uint2 q0 = xp[0], q1 = xp[1], q2 = xp[2];
            float xv[12];
            xv[0] = lo16f(q0.x); xv[1]  = hi16f(q0.x);
            xv[2] = lo16f(q0.y); xv[3]  = hi16f(q0.y);
            xv[4] = lo16f(q1.x); xv[5]  = hi16f(q1.x);
            xv[6] = lo16f(q1.y); xv[7]  = hi16f(q1.y);
            xv[8] = lo16f(q2.x); xv[9]  = hi16f(q2.x);
            xv[10] = lo16f(q2.y); xv[11] = hi16f(q2.y);
            float a0 = zs[(ug << 5) + v];
            float a1 = zs[((8 + ug) << 5) + v];
            float a2 = zs[((16 + ug) << 5) + v];
            float a3 = zs[((24 + ug) << 5) + v];
#pragma unroll
            for (int m = 0; m < 12; ++m) {
                acc[0][m] += a0 * xv[m];
                acc[1][m] += a1 * xv[m];
                acc[2][m] += a2 * xv[m];
                acc[3][m] += a3 * xv[m];
            }
        }
        float* __restrict__ obase = out + (size_t)blk * (32 * 384);
#pragma unroll
        for (int j = 0; j < 4; ++j) {
            const int u = (j << 3) + ug;
            float* orow = obase + u * 384 + l * 12;
            float4 o0 = make_float4(acc[j][0], acc[j][1], acc[j][2],  acc[j][3]);
            float4 o1 = make_float4(acc[j][4], acc[j][5], acc[j][6],  acc[j][7]);
            float4 o2 = make_float4(acc[j][8], acc[j][9], acc[j][10], acc[j][11]);
            *(float4*)(orow)     = o0;
            *(float4*)(orow + 4) = o1;
            *(float4*)(orow + 8) = o2;
        }
    }
}

// ---------------------------------------------------------------------------
extern "C" void kernel_launch(void* const* d_in, const int* in_sizes, int n_in,
                              void* d_out, int out_size, void* d_ws, size_t ws_size,
                              hipStream_t stream) {
    const float* x   = (const float*)d_in[0];
    const float* W2d = (const float*)d_in[1];
    const float* b2d = (const float*)d_in[2];
    const float* W1d = (const float*)d_in[3];
    const float* b1d = (const float*)d_in[4];
    float* out = (float*)d_out;

    const size_t wt_bytes = 8 * 8 * 128 * 8 * sizeof(ushort_t);   // 131072
    if (ws_size >= wt_bytes) {
        ushort_t* Wt = (ushort_t*)d_ws;
        w1d_to_bf16<<<32, 256, 0, stream>>>(W1d, Wt);
        dynamixer_fused<true><<<4096, 256, 0, stream>>>(x, W2d, b2d, W1d, b1d, Wt, out);
    } else {
        dynamixer_fused<false><<<4096, 256, 0, stream>>>(x, W2d, b2d, W1d, b1d, nullptr, out);
    }
}

// Round 3
// 149.085 us; speedup vs baseline: 1.6537x; 1.6537x over previous
//
#include <hip/hip_runtime.h>
#include <hip/hip_bf16.h>
#include <stdint.h>

typedef unsigned short ushort_t;

__device__ __forceinline__ float lo16f(uint32_t u) { return __uint_as_float(u << 16); }
__device__ __forceinline__ float hi16f(uint32_t u) { return __uint_as_float(u & 0xFFFF0000u); }
__device__ __forceinline__ float2 up2(uint32_t u) {
    return make_float2(__uint_as_float(u << 16), __uint_as_float(u & 0xFFFF0000u));
}
__device__ __forceinline__ uint32_t pk_bf16(float a, float b) {
    uint32_t r;
    asm("v_cvt_pk_bf16_f32 %0, %1, %2" : "=v"(r) : "v"(a), "v"(b));
    return r;   // lo16 = bf16(a), hi16 = bf16(b)
}

// ---------------------------------------------------------------------------
// Pre-kernel (35 blocks):
//  blocks 0-31 : W1d (1024x64 fp32) -> Wt bf16 [g][k][o][j]  (131072 B)
//  blocks 32-34: W2d (16x384 fp32)  -> W2b bf16 [16][48] uint4 (12288 B)
// ---------------------------------------------------------------------------
__global__ void __launch_bounds__(256) prep_weights(const float* __restrict__ W1d,
                                                    const float* __restrict__ W2d,
                                                    ushort_t* __restrict__ Wt,
                                                    uint4* __restrict__ W2b) {
    int bid = blockIdx.x;
    if (bid < 32) {
        int t = bid * 256 + threadIdx.x;          // 0..8191
        int g = t >> 10, k = (t >> 7) & 7, o = t & 127;
        const float* src = W1d + (((g << 7) + o) << 6) + (k << 3);
        ushort_t* dst = Wt + ((((g << 3) + k) << 7) + o) * 8;
#pragma unroll
        for (int j = 0; j < 8; ++j) {
            uint32_t u = __float_as_uint(src[j]);
            uint32_t r = (u + 0x7FFFu + ((u >> 16) & 1u)) >> 16;   // RN to bf16
            dst[j] = (ushort_t)r;
        }
    } else {
        int idx = (bid - 32) * 256 + threadIdx.x;  // 0..767
        const float4* s = (const float4*)W2d + idx * 2;
        float4 A = s[0], B = s[1];
        uint4 p;
        p.x = pk_bf16(A.x, A.y); p.y = pk_bf16(A.z, A.w);
        p.z = pk_bf16(B.x, B.y); p.w = pk_bf16(B.z, B.w);
        W2b[idx] = p;
    }
}

// ---------------------------------------------------------------------------
// Fused kernel: one block (256 thr) per (b,h).  ONE __syncthreads total;
// phases 2->3->4 exchange intra-wave only (wave w: e 4w..4w+3 -> groups
// 2w,2w+1 -> attn rows 8w..8w+7), fenced with s_waitcnt lgkmcnt(0).
// LDS: xs 24576 (bf16, XOR-swizzled chunks) + ys 2048 + zs 4096 = 30720
//   -> 5 blocks/CU.
// ---------------------------------------------------------------------------
template <bool WBF>
__global__ void __launch_bounds__(256, 5) dynamixer_fused(
    const float* __restrict__ x,
    const float* __restrict__ W2d,
    const float* __restrict__ b2d,
    const float* __restrict__ W1d,
    const float* __restrict__ b1d,
    const ushort_t* __restrict__ Wt,
    const uint4* __restrict__ W2b,
    float* __restrict__ out)
{
    __shared__ uint4 xs4[32 * 48];          // bf16 x tile, 48 chunks/row, swizzled
    __shared__ alignas(16) float ys[512];   // y, flat e*32+w == g*64+c
    __shared__ alignas(16) float zs[1024];  // attn[u][v]

    const int t = threadIdx.x;
    const int blk = blockIdx.x;                           // b*32 + h
    const float* __restrict__ xsrc = x + (size_t)blk * (32 * 384);
    const ushort_t* const xs16 = (const ushort_t*)xs4;

    // ---------------- phase 1: stage x as bf16 (swizzled chunks) ----------
    {
        const float4* __restrict__ s4 = (const float4*)xsrc;
#pragma unroll
        for (int k = 0; k < 6; ++k) {
            int p = t + (k << 8);                         // pair index 0..1535
            int row = p / 48, c = p - row * 48;
            float4 A = s4[2 * p];
            float4 B = s4[2 * p + 1];
            uint4 pk;
            pk.x = pk_bf16(A.x, A.y); pk.y = pk_bf16(A.z, A.w);
            pk.z = pk_bf16(B.x, B.y); pk.w = pk_bf16(B.z, B.w);
            xs4[row * 48 + (c ^ ((row >> 1) & 7))] = pk;
        }
    }
    __syncthreads();

    const int wid = t >> 6, lane = t & 63;

    // ---------------- phase 2: conv2d (y); 2e x 2w x split-K tiling --------
    {
        const int kh = lane >> 5, eh = (lane >> 4) & 1, wp = lane & 15;
        const int E = 4 * wid + 2 * eh;                   // e, e+1
        const int f = wp & 7;
        const uint4* __restrict__ xr0 = xs4 + (2 * wp) * 48;
        const uint4* __restrict__ xr1 = xr0 + 48;
        float2 a00 = {0.f, 0.f}, a01 = {0.f, 0.f}, a10 = {0.f, 0.f}, a11 = {0.f, 0.f};

        if (WBF) {
            const uint4* __restrict__ w0 = W2b + E * 48;
            const uint4* __restrict__ w1 = w0 + 48;
#pragma unroll 8
            for (int i = 0; i < 24; ++i) {
                const int c = 2 * i + kh;
                uint4 xa = xr0[c ^ f], xb = xr1[c ^ f];
                uint4 wa = w0[c],      wb = w1[c];
                float2 xa0 = up2(xa.x), xa1 = up2(xa.y), xa2 = up2(xa.z), xa3 = up2(xa.w);
                float2 xb0 = up2(xb.x), xb1 = up2(xb.y), xb2 = up2(xb.z), xb3 = up2(xb.w);
                float2 wa0 = up2(wa.x), wa1 = up2(wa.y), wa2 = up2(wa.z), wa3 = up2(wa.w);
                float2 wb0 = up2(wb.x), wb1 = up2(wb.y), wb2 = up2(wb.z), wb3 = up2(wb.w);
                a00 += wa0 * xa0; a00 += wa1 * xa1; a00 += wa2 * xa2; a00 += wa3 * xa3;
                a01 += wa0 * xb0; a01 += wa1 * xb1; a01 += wa2 * xb2; a01 += wa3 * xb3;
                a10 += wb0 * xa0; a10 += wb1 * xa1; a10 += wb2 * xa2; a10 += wb3 * xa3;
                a11 += wb0 * xb0; a11 += wb1 * xb1; a11 += wb2 * xb2; a11 += wb3 * xb3;
            }
        } else {
            const float2* __restrict__ w0f = (const float2*)W2d + E * 192;
            const float2* __restrict__ w1f = w0f + 192;
#pragma unroll 4
            for (int i = 0; i < 24; ++i) {
                const int c = 2 * i + kh;
                uint4 xa = xr0[c ^ f], xb = xr1[c ^ f];
                float2 xa0 = up2(xa.x), xa1 = up2(xa.y), xa2 = up2(xa.z), xa3 = up2(xa.w);
                float2 xb0 = up2(xb.x), xb1 = up2(xb.y), xb2 = up2(xb.z), xb3 = up2(xb.w);
                float2 wa0 = w0f[4*c], wa1 = w0f[4*c+1], wa2 = w0f[4*c+2], wa3 = w0f[4*c+3];
                float2 wb0 = w1f[4*c], wb1 = w1f[4*c+1], wb2 = w1f[4*c+2], wb3 = w1f[4*c+3];
                a00 += wa0 * xa0; a00 += wa1 * xa1; a00 += wa2 * xa2; a00 += wa3 * xa3;
                a01 += wa0 * xb0; a01 += wa1 * xb1; a01 += wa2 * xb2; a01 += wa3 * xb3;
                a10 += wb0 * xa0; a10 += wb1 * xa1; a10 += wb2 * xa2; a10 += wb3 * xa3;
                a11 += wb0 * xb0; a11 += wb1 * xb1; a11 += wb2 * xb2; a11 += wb3 * xb3;
            }
        }
        float s00 = a00.x + a00.y, s01 = a01.x + a01.y;
        float s10 = a10.x + a10.y, s11 = a11.x + a11.y;
        s00 += __shfl_xor(s00, 32);
        s01 += __shfl_xor(s01, 32);
        s10 += __shfl_xor(s10, 32);
        s11 += __shfl_xor(s11, 32);
        float bb0 = b2d[E], bb1 = b2d[E + 1];
        *(float2*)&ys[E * 32 + 2 * wp]       = make_float2(s00 + bb0, s01 + bb0);
        *(float2*)&ys[(E + 1) * 32 + 2 * wp] = make_float2(s10 + bb1, s11 + bb1);
    }
    asm volatile("s_waitcnt lgkmcnt(0)" ::: "memory");
    __builtin_amdgcn_sched_barrier(0);

    // ---------------- phase 3: conv1d (z) + softmax -> zs (intra-wave) -----
    {
        const int g = t >> 5, l = t & 31;                 // g = 2*wid + gh
        float acc[4] = {0.f, 0.f, 0.f, 0.f};
        if (WBF) {
            const uint4* __restrict__ wpt = (const uint4*)Wt + (g << 10);
#pragma unroll
            for (int k = 0; k < 8; ++k) {
                float4 ya = *(const float4*)&ys[(g << 6) + (k << 3)];
                float4 yb = *(const float4*)&ys[(g << 6) + (k << 3) + 4];
#pragma unroll
                for (int j = 0; j < 4; ++j) {
                    uint4 wq = wpt[(k << 7) + l + (j << 5)];
                    acc[j] += lo16f(wq.x) * ya.x; acc[j] += hi16f(wq.x) * ya.y;
                    acc[j] += lo16f(wq.y) * ya.z; acc[j] += hi16f(wq.y) * ya.w;
                    acc[j] += lo16f(wq.z) * yb.x; acc[j] += hi16f(wq.z) * yb.y;
                    acc[j] += lo16f(wq.w) * yb.z; acc[j] += hi16f(wq.w) * yb.w;
                }
            }
        } else {
#pragma unroll
            for (int k = 0; k < 8; ++k) {
                float4 ya = *(const float4*)&ys[(g << 6) + (k << 3)];
                float4 yb = *(const float4*)&ys[(g << 6) + (k << 3) + 4];
#pragma unroll
                for (int j = 0; j < 4; ++j) {
                    const float* wr = W1d + (((g << 7) + l + (j << 5)) << 6) + (k << 3);
                    float4 wa = *(const float4*)wr;
                    float4 wb = *(const float4*)(wr + 4);
                    acc[j] += wa.x * ya.x; acc[j] += wa.y * ya.y;
                    acc[j] += wa.z * ya.z; acc[j] += wa.w * ya.w;
                    acc[j] += wb.x * yb.x; acc[j] += wb.y * yb.y;
                    acc[j] += wb.z * yb.z; acc[j] += wb.w * yb.w;
                }
            }
        }
#pragma unroll
        for (int j = 0; j < 4; ++j) acc[j] += b1d[(g << 7) + (j << 5) + l];

        // softmax over v (= lane within 32-lane group)
#pragma unroll
        for (int j = 0; j < 4; ++j) {
            float m = acc[j];
#pragma unroll
            for (int s = 16; s >= 1; s >>= 1) m = fmaxf(m, __shfl_xor(m, s, 32));
            float p = __expf(acc[j] - m);
            float ssum = p;
#pragma unroll
            for (int s = 16; s >= 1; s >>= 1) ssum += __shfl_xor(ssum, s, 32);
            zs[(((g << 2) + j) << 5) + l] = __fdividef(p, ssum);   // u = 4g+j
        }
    }
    asm volatile("s_waitcnt lgkmcnt(0)" ::: "memory");
    __builtin_amdgcn_sched_barrier(0);

    // ---------------- phase 4: out = attn . x  (intra-wave rows) ----------
    {
        const int gh = lane >> 5, l = lane & 31;
        const int u0 = 8 * wid + 4 * gh;                  // 4 rows per lane
        float2 acc[4][6];
#pragma unroll
        for (int j = 0; j < 4; ++j)
#pragma unroll
            for (int m = 0; m < 6; ++m) acc[j][m] = make_float2(0.f, 0.f);

#pragma unroll 2
        for (int vq = 0; vq < 8; ++vq) {
            float4 A0 = *(const float4*)&zs[(u0 + 0) * 32 + vq * 4];
            float4 A1 = *(const float4*)&zs[(u0 + 1) * 32 + vq * 4];
            float4 A2 = *(const float4*)&zs[(u0 + 2) * 32 + vq * 4];
            float4 A3 = *(const float4*)&zs[(u0 + 3) * 32 + vq * 4];
            float a0v[4] = {A0.x, A0.y, A0.z, A0.w};
            float a1v[4] = {A1.x, A1.y, A1.z, A1.w};
            float a2v[4] = {A2.x, A2.y, A2.z, A2.w};
            float a3v[4] = {A3.x, A3.y, A3.z, A3.w};
#pragma unroll
            for (int vi = 0; vi < 4; ++vi) {
                const int v = vq * 4 + vi;
                const int fx = ((v >> 1) & 7) << 3;       // swizzle on ushort idx bits 3-5
                const ushort_t* xr = xs16 + v * 384;
                uint2 q0 = *(const uint2*)(xr + ((l * 4) ^ fx));
                uint2 q1 = *(const uint2*)(xr + ((l * 4 + 128) ^ fx));
                uint2 q2 = *(const uint2*)(xr + ((l * 4 + 256) ^ fx));
                float2 xv[6];
                xv[0] = up2(q0.x); xv[1] = up2(q0.y);
                xv[2] = up2(q1.x); xv[3] = up2(q1.y);
                xv[4] = up2(q2.x); xv[5] = up2(q2.y);
                float av[4] = {a0v[vi], a1v[vi], a2v[vi], a3v[vi]};
#pragma unroll
                for (int j = 0; j < 4; ++j) {
                    float2 bj = make_float2(av[j], av[j]);
#pragma unroll
                    for (int m = 0; m < 6; ++m) acc[j][m] += bj * xv[m];
                }
            }
        }
        float* __restrict__ obase = out + (size_t)blk * (32 * 384);
#pragma unroll
        for (int j = 0; j < 4; ++j) {
            float* orow = obase + (u0 + j) * 384;
#pragma unroll
            for (int k = 0; k < 3; ++k) {
                float4 o = make_float4(acc[j][2 * k].x, acc[j][2 * k].y,
                                       acc[j][2 * k + 1].x, acc[j][2 * k + 1].y);
                *(float4*)&orow[(l + 32 * k) * 4] = o;    // 512B-contiguous per half-wave
            }
        }
    }
}

// ---------------------------------------------------------------------------
extern "C" void kernel_launch(void* const* d_in, const int* in_sizes, int n_in,
                              void* d_out, int out_size, void* d_ws, size_t ws_size,
                              hipStream_t stream) {
    const float* x   = (const float*)d_in[0];
    const float* W2d = (const float*)d_in[1];
    const float* b2d = (const float*)d_in[2];
    const float* W1d = (const float*)d_in[3];
    const float* b1d = (const float*)d_in[4];
    float* out = (float*)d_out;

    const size_t wt_bytes  = 8 * 8 * 128 * 8 * sizeof(ushort_t);   // 131072
    const size_t w2b_bytes = 16 * 48 * sizeof(uint4);              // 12288
    if (ws_size >= wt_bytes + w2b_bytes) {
        ushort_t* Wt = (ushort_t*)d_ws;
        uint4* W2b = (uint4*)((char*)d_ws + wt_bytes);
        prep_weights<<<35, 256, 0, stream>>>(W1d, W2d, Wt, W2b);
        dynamixer_fused<true><<<4096, 256, 0, stream>>>(x, W2d, b2d, W1d, b1d, Wt, W2b, out);
    } else {
        dynamixer_fused<false><<<4096, 256, 0, stream>>>(x, W2d, b2d, W1d, b1d, nullptr, nullptr, out);
    }
}

// Round 4
// 111.757 us; speedup vs baseline: 2.2060x; 1.3340x over previous
//
#include <hip/hip_runtime.h>
#include <stdint.h>

typedef unsigned short u16t;
typedef __attribute__((ext_vector_type(8))) short bf16x8;
typedef __attribute__((ext_vector_type(4))) float f32x4;
typedef __attribute__((ext_vector_type(16))) float f32x16;

__device__ __forceinline__ float lo16f(uint32_t u) { return __uint_as_float(u << 16); }
__device__ __forceinline__ float hi16f(uint32_t u) { return __uint_as_float(u & 0xFFFF0000u); }
__device__ __forceinline__ float2 up2(uint32_t u) {
    return make_float2(__uint_as_float(u << 16), __uint_as_float(u & 0xFFFF0000u));
}
__device__ __forceinline__ uint32_t pk_bf16(float a, float b) {
    uint32_t r;
    asm("v_cvt_pk_bf16_f32 %0, %1, %2" : "=v"(r) : "v"(a), "v"(b));
    return r;   // lo16 = bf16(a) RNE, hi16 = bf16(b)
}

// ---------------------------------------------------------------------------
// Pre-kernel (35 blocks):
//  blocks 0-31 : W1d (1024x64 fp32) -> Wt bf16 [g][k][o][j]   (131072 B)
//  blocks 32-34: W2d (16x384 fp32)  -> W2b bf16 [16][384] row-major (12288 B)
// ---------------------------------------------------------------------------
__global__ void __launch_bounds__(256) prep_weights(const float* __restrict__ W1d,
                                                    const float* __restrict__ W2d,
                                                    u16t* __restrict__ Wt,
                                                    uint4* __restrict__ W2b) {
    int bid = blockIdx.x;
    if (bid < 32) {
        int t = bid * 256 + threadIdx.x;          // 0..8191
        int g = t >> 10, k = (t >> 7) & 7, o = t & 127;
        const float* src = W1d + (((g << 7) + o) << 6) + (k << 3);
        u16t* dst = Wt + ((((g << 3) + k) << 7) + o) * 8;
#pragma unroll
        for (int j = 0; j < 8; ++j) {
            uint32_t u = __float_as_uint(src[j]);
            uint32_t r = (u + 0x7FFFu + ((u >> 16) & 1u)) >> 16;   // RN to bf16
            dst[j] = (u16t)r;
        }
    } else {
        int idx = (bid - 32) * 256 + threadIdx.x;  // 0..767 (chunks of 8 f32)
        const float4* s = (const float4*)W2d + idx * 2;
        float4 A = s[0], B = s[1];
        uint4 p;
        p.x = pk_bf16(A.x, A.y); p.y = pk_bf16(A.z, A.w);
        p.z = pk_bf16(B.x, B.y); p.w = pk_bf16(B.z, B.w);
        W2b[idx] = p;
    }
}

// ---------------------------------------------------------------------------
// Fused kernel: one block (256 thr) per (b,h).
//  phase 1: stage x[b,h] (32x384 f32) -> bf16 LDS xs16[32][392]
//  phase 2: y = W2d . x^T via mfma_16x16x32_bf16 (per-wave dup, e-slice write)
//  phase 3: conv1d + softmax (VALU, float2 pk-FMA) -> attn bf16 zs16[32][32]
//  phase 4: out = attn . x via mfma_32x32x16_bf16 (B gathered from xs)
// LDS: 25088 + 2048 + 2048 = 29184 B -> 5 blocks/CU.  Barriers: 2.
// ---------------------------------------------------------------------------
template <bool WBF>
__global__ void __launch_bounds__(256, 5) dynamixer_fused(
    const float* __restrict__ x,
    const float* __restrict__ W2d,
    const float* __restrict__ b2d,
    const float* __restrict__ W1d,
    const float* __restrict__ b1d,
    const u16t* __restrict__ Wt,
    const u16t* __restrict__ W2b,
    float* __restrict__ out)
{
    __shared__ u16t xs16[32 * 392];          // bf16 x tile, row stride 392
    __shared__ alignas(16) float ys[512];    // y, flat e*32+w
    __shared__ alignas(16) u16t zs16[1024];  // attn bf16 [u][v]

    const int t = threadIdx.x;
    const int blk = blockIdx.x;                           // b*32 + h
    const float* __restrict__ xsrc = x + (size_t)blk * 12288;

    // ---------------- phase 1: stage x as bf16 ----------------
    {
        const float4* __restrict__ s4 = (const float4*)xsrc;
#pragma unroll
        for (int k = 0; k < 6; ++k) {
            int p = t + (k << 8);                         // pair index 0..1535
            int row = p / 48, c = p - row * 48;           // 48 chunks of 8/row
            float4 A4 = s4[2 * p], B4 = s4[2 * p + 1];
            uint4 pk;
            pk.x = pk_bf16(A4.x, A4.y); pk.y = pk_bf16(A4.z, A4.w);
            pk.z = pk_bf16(B4.x, B4.y); pk.w = pk_bf16(B4.z, B4.w);
            *(uint4*)&xs16[row * 392 + c * 8] = pk;
        }
    }
    __syncthreads();

    const int wid = t >> 6, lane = t & 63;

    // ---------------- phase 2: conv2d via MFMA 16x16x32 ----------------
    {
        const int g4 = lane >> 4, m = lane & 15;          // A row=e=m, B col=w=m
        f32x4 c0, c1;
#pragma unroll
        for (int r = 0; r < 4; ++r) { c0[r] = 0.f; c1[r] = 0.f; }
#pragma unroll 4
        for (int ks = 0; ks < 12; ++ks) {
            const int d0 = ks * 32 + g4 * 8;
            bf16x8 a;
            if (WBF) {
                a = *(const bf16x8*)&W2b[m * 384 + d0];
            } else {
                const float* wf = W2d + m * 384 + d0;
                float4 wa = *(const float4*)wf, wb = *(const float4*)(wf + 4);
                union { uint4 u; bf16x8 v; } cvt;
                cvt.u.x = pk_bf16(wa.x, wa.y); cvt.u.y = pk_bf16(wa.z, wa.w);
                cvt.u.z = pk_bf16(wb.x, wb.y); cvt.u.w = pk_bf16(wb.z, wb.w);
                a = cvt.v;
            }
            bf16x8 b0 = *(const bf16x8*)&xs16[m * 392 + d0];
            bf16x8 b1 = *(const bf16x8*)&xs16[(m + 16) * 392 + d0];
            c0 = __builtin_amdgcn_mfma_f32_16x16x32_bf16(a, b0, c0, 0, 0, 0);
            c1 = __builtin_amdgcn_mfma_f32_16x16x32_bf16(a, b1, c1, 0, 0, 0);
        }
        // write only this wave's e-slice [4*wid, 4*wid+4): C row=(l>>4)*4+r
        if (g4 == wid) {
            float4 bb = *(const float4*)&b2d[wid * 4];
            float bbv[4] = {bb.x, bb.y, bb.z, bb.w};
#pragma unroll
            for (int r = 0; r < 4; ++r) {
                ys[(4 * wid + r) * 32 + m]      = c0[r] + bbv[r];
                ys[(4 * wid + r) * 32 + 16 + m] = c1[r] + bbv[r];
            }
        }
    }
    // no barrier: ys slice e[4w..4w+3] feeds only this wave's g in {2w,2w+1}

    // ---------------- phase 3: conv1d (z) + softmax -> attn bf16 ----------
    {
        const int g = t >> 5, l = t & 31;
        float2 ac2[4];
#pragma unroll
        for (int j = 0; j < 4; ++j) ac2[j] = make_float2(0.f, 0.f);
        if (WBF) {
            const uint4* __restrict__ wpt = (const uint4*)Wt + (g << 10);
#pragma unroll
            for (int k = 0; k < 8; ++k) {
                const float2* yp = (const float2*)&ys[(g << 6) + (k << 3)];
                float2 y0 = yp[0], y1 = yp[1], y2 = yp[2], y3 = yp[3];
#pragma unroll
                for (int j = 0; j < 4; ++j) {
                    uint4 wq = wpt[(k << 7) + l + (j << 5)];
                    ac2[j] += up2(wq.x) * y0;
                    ac2[j] += up2(wq.y) * y1;
                    ac2[j] += up2(wq.z) * y2;
                    ac2[j] += up2(wq.w) * y3;
                }
            }
        } else {
#pragma unroll
            for (int k = 0; k < 8; ++k) {
                const float2* yp = (const float2*)&ys[(g << 6) + (k << 3)];
                float2 y0 = yp[0], y1 = yp[1], y2 = yp[2], y3 = yp[3];
#pragma unroll
                for (int j = 0; j < 4; ++j) {
                    const float2* wr = (const float2*)(W1d + (((g << 7) + l + (j << 5)) << 6) + (k << 3));
                    ac2[j] += wr[0] * y0;
                    ac2[j] += wr[1] * y1;
                    ac2[j] += wr[2] * y2;
                    ac2[j] += wr[3] * y3;
                }
            }
        }
        float acc[4];
#pragma unroll
        for (int j = 0; j < 4; ++j)
            acc[j] = ac2[j].x + ac2[j].y + b1d[(g << 7) + (j << 5) + l];

        // softmax over v (= lane within 32-lane group), row u = 4g+j
#pragma unroll
        for (int j = 0; j < 4; ++j) {
            float mx = acc[j];
#pragma unroll
            for (int s = 16; s >= 1; s >>= 1) mx = fmaxf(mx, __shfl_xor(mx, s, 32));
            float p = __expf(acc[j] - mx);
            float ssum = p;
#pragma unroll
            for (int s = 16; s >= 1; s >>= 1) ssum += __shfl_xor(ssum, s, 32);
            float pv = __fdividef(p, ssum);
            zs16[((g << 2) + j) * 32 + l] = (u16t)pk_bf16(pv, pv);
        }
    }
    __syncthreads();

    // ---------------- phase 4: out = attn . x via MFMA 32x32x16 ----------
    {
        const int g2 = lane >> 5, l31 = lane & 31;
        // A frags: attn[u = l31][k = g2*8 + j (+16)]
        bf16x8 A0 = *(const bf16x8*)&zs16[l31 * 32 + g2 * 8];
        bf16x8 A1 = *(const bf16x8*)&zs16[l31 * 32 + 16 + g2 * 8];
        float* __restrict__ obase = out + (size_t)blk * 12288;
        for (int i = 0; i < 3; ++i) {
            const int d = (wid * 3 + i) * 32 + l31;
            const u16t* __restrict__ xc = xs16 + d;
            bf16x8 B0, B1;
#pragma unroll
            for (int j = 0; j < 8; ++j) {
                B0[j] = (short)xc[(g2 * 8 + j) * 392];
                B1[j] = (short)xc[(16 + g2 * 8 + j) * 392];
            }
            f32x16 acc16;
#pragma unroll
            for (int r = 0; r < 16; ++r) acc16[r] = 0.f;
            acc16 = __builtin_amdgcn_mfma_f32_32x32x16_bf16(A0, B0, acc16, 0, 0, 0);
            acc16 = __builtin_amdgcn_mfma_f32_32x32x16_bf16(A1, B1, acc16, 0, 0, 0);
#pragma unroll
            for (int r = 0; r < 16; ++r) {
                const int u = (r & 3) + 8 * (r >> 2) + 4 * g2;
                obase[u * 384 + d] = acc16[r];
            }
        }
    }
}

// ---------------------------------------------------------------------------
extern "C" void kernel_launch(void* const* d_in, const int* in_sizes, int n_in,
                              void* d_out, int out_size, void* d_ws, size_t ws_size,
                              hipStream_t stream) {
    const float* x   = (const float*)d_in[0];
    const float* W2d = (const float*)d_in[1];
    const float* b2d = (const float*)d_in[2];
    const float* W1d = (const float*)d_in[3];
    const float* b1d = (const float*)d_in[4];
    float* out = (float*)d_out;

    const size_t wt_bytes  = 8 * 8 * 128 * 8 * sizeof(u16t);   // 131072
    const size_t w2b_bytes = 16 * 384 * sizeof(u16t);          // 12288
    if (ws_size >= wt_bytes + w2b_bytes) {
        u16t* Wt = (u16t*)d_ws;
        u16t* W2b = (u16t*)((char*)d_ws + wt_bytes);
        prep_weights<<<35, 256, 0, stream>>>(W1d, W2d, Wt, (uint4*)W2b);
        dynamixer_fused<true><<<4096, 256, 0, stream>>>(x, W2d, b2d, W1d, b1d, Wt, W2b, out);
    } else {
        dynamixer_fused<false><<<4096, 256, 0, stream>>>(x, W2d, b2d, W1d, b1d, nullptr, nullptr, out);
    }
}